// Round 4
// baseline (140.562 us; speedup 1.0000x reference)
//
#include <hip/hip_runtime.h>
#include <hip/hip_bf16.h>
#include <math.h>

#define EMBED 768
#define NTOK  4096
#define NB    4
#define ROWS  16384          // 4 * 4096
#define CN    192            // Q(64)|K(64)|V(64)

typedef __attribute__((ext_vector_type(8))) short bf16x8;          // 8 bf16 = 4 VGPR
typedef __attribute__((ext_vector_type(8))) unsigned short u16x8;  // store vector
typedef __attribute__((ext_vector_type(4))) float f32x4;           // MFMA acc

// Split fp32 into h + l bf16 (RNE both, tie-parity exact): used in wprep.
__device__ inline void split2(float f, short& h, short& l) {
  union { float f; unsigned u; } a; a.f = f;
  unsigned r = (a.u + 0x7FFFu + ((a.u >> 16) & 1u)) & 0xFFFF0000u;
  h = (short)(r >> 16);
  union { unsigned u; float f; } hf; hf.u = r;
  union { float f; unsigned u; } b; b.f = f - hf.f;
  l = (short)((b.u + 0x7FFFu + ((b.u >> 16) & 1u)) >> 16);
}

// ---------------------------------------------------------------------------
// W prep: LDS-staged transpose, coalesced both sides.
// Layout: Wt[ks][plane][q][n][j] bf16, elem = ks*12288 + p*6144 + q*1536 + n*8 + j
//   where k = ks*32 + q*8 + j, n in [0,192). Quarter-wave reads in qkv are
//   16 consecutive 16B slots (256 B segments). Also zeroes Vsum.
// ---------------------------------------------------------------------------
__global__ __launch_bounds__(256) void wprep(const float* __restrict__ Wq,
                                             const float* __restrict__ Wk,
                                             const float* __restrict__ Wv,
                                             unsigned short* __restrict__ Wt,
                                             float* __restrict__ Vsum) {
  __shared__ float tile[32 * 64];   // W[ks*32 .. +32][0..64]
  const int b   = blockIdx.x;
  const int mat = b / 24;           // 0=Wq 1=Wk 2=Wv
  const int ks  = b - mat * 24;
  const float* W = (mat == 0) ? Wq : (mat == 1) ? Wk : Wv;
  const int t = threadIdx.x;

  const float4* src = (const float4*)(W + ks * 2048);
  ((float4*)tile)[t]       = src[t];
  ((float4*)tile)[t + 256] = src[t + 256];
  __syncthreads();

  const int q    = t >> 6;          // k-oct 0..3
  const int nloc = t & 63;          // 0..63 within this matrix
  u16x8 hv, lv;
#pragma unroll
  for (int j = 0; j < 8; ++j) {
    short h, l;
    split2(tile[(q * 8 + j) * 64 + nloc], h, l);
    hv[j] = (unsigned short)h;
    lv[j] = (unsigned short)l;
  }
  const size_t base = (size_t)ks * 12288 + (size_t)q * 1536 + (size_t)(mat * 64 + nloc) * 8;
  *(u16x8*)(Wt + base)        = hv;
  *(u16x8*)(Wt + base + 6144) = lv;

  if (b == 0 && t < NB * 64) Vsum[t] = 0.f;
}

// ---------------------------------------------------------------------------
// MFMA GEMM: C[16384][192] = x @ W + bias, split-bf16 (3 MFMA passes).
// NO LDS, NO barriers: 512 blocks x 512 threads = 8 free-running waves
// (2 m-halves x 4 n-slices), wave tile 16x48. B frags read directly from
// L2-resident Wt into NAMED registers (scratch-proof), 1-deep ping-pong;
// compiler emits counted vmcnt and pipelines across k-steps. 4 waves/SIMD
// (launch_bounds(512,4), ~100 VGPR) hides L2/HBM latency by TLP.
// Fused Vsum epilogue.
// ---------------------------------------------------------------------------

// HW RNE split: f = h + l, both planes RNE.
__device__ inline void splitHW(float f, short& h, short& l) {
  __hip_bfloat16 hb = __float2bfloat16(f);
  float hf = __bfloat162float(hb);
  __hip_bfloat16 lb = __float2bfloat16(f - hf);
  h = __builtin_bit_cast(short, hb);
  l = __builtin_bit_cast(short, lb);
}

__device__ inline void cvt8hw(const float4 f0, const float4 f1, bf16x8& h, bf16x8& l) {
  short hh, ll;
  splitHW(f0.x, hh, ll); h[0] = hh; l[0] = ll;
  splitHW(f0.y, hh, ll); h[1] = hh; l[1] = ll;
  splitHW(f0.z, hh, ll); h[2] = hh; l[2] = ll;
  splitHW(f0.w, hh, ll); h[3] = hh; l[3] = ll;
  splitHW(f1.x, hh, ll); h[4] = hh; l[4] = ll;
  splitHW(f1.y, hh, ll); h[5] = hh; l[5] = ll;
  splitHW(f1.z, hh, ll); h[6] = hh; l[6] = ll;
  splitHW(f1.w, hh, ll); h[7] = hh; l[7] = ll;
}

// B frag loads for k-step KS into 6 named regs. Offsets in bf16x8 units:
// +16 per nt (128 shorts), +768 for low plane (6144 shorts).
#define LOADB(H0, L0, H1, L1, H2, L2, KS) do {                        \
    const bf16x8* _p = (const bf16x8*)(Bb + (size_t)(KS) * 12288);    \
    H0 = _p[0];  L0 = _p[768];                                        \
    H1 = _p[16]; L1 = _p[784];                                        \
    H2 = _p[32]; L2 = _p[800];                                        \
  } while (0)

#define LOADA(A0, A1, KS) do {                                        \
    A0 = *(const float4*)(xa + (KS) * 32);                            \
    A1 = *(const float4*)(xa + (KS) * 32 + 4);                        \
  } while (0)

#define COMPUTE(A0, A1, H0, L0, H1, L1, H2, L2) do {                              \
    bf16x8 ah, al;                                                                \
    cvt8hw(A0, A1, ah, al);                                                       \
    acc0 = __builtin_amdgcn_mfma_f32_16x16x32_bf16(ah, H0, acc0, 0, 0, 0);        \
    acc1 = __builtin_amdgcn_mfma_f32_16x16x32_bf16(ah, H1, acc1, 0, 0, 0);        \
    acc2 = __builtin_amdgcn_mfma_f32_16x16x32_bf16(ah, H2, acc2, 0, 0, 0);        \
    acc0 = __builtin_amdgcn_mfma_f32_16x16x32_bf16(ah, L0, acc0, 0, 0, 0);        \
    acc1 = __builtin_amdgcn_mfma_f32_16x16x32_bf16(ah, L1, acc1, 0, 0, 0);        \
    acc2 = __builtin_amdgcn_mfma_f32_16x16x32_bf16(ah, L2, acc2, 0, 0, 0);        \
    acc0 = __builtin_amdgcn_mfma_f32_16x16x32_bf16(al, H0, acc0, 0, 0, 0);        \
    acc1 = __builtin_amdgcn_mfma_f32_16x16x32_bf16(al, H1, acc1, 0, 0, 0);        \
    acc2 = __builtin_amdgcn_mfma_f32_16x16x32_bf16(al, H2, acc2, 0, 0, 0);        \
  } while (0)

__global__ __launch_bounds__(512, 4) void qkv_mfma(const float* __restrict__ x,
                                                   const unsigned short* __restrict__ Wtu,
                                                   const float* __restrict__ bq,
                                                   const float* __restrict__ bk,
                                                   const float* __restrict__ bv,
                                                   float* __restrict__ C,
                                                   float* __restrict__ Vsum) {
  const int tid  = threadIdx.x;
  const int lane = tid & 63;
  const int wv   = tid >> 6;          // 0..7
  const int mh   = wv & 1;            // m-half (16 rows)
  const int wn   = wv >> 1;           // n-slice 0..3 (48 cols)
  const int ml   = lane & 15;
  const int q    = lane >> 4;         // k-oct
  const int r0   = blockIdx.x * 32;

  f32x4 acc0 = {0.f,0.f,0.f,0.f}, acc1 = {0.f,0.f,0.f,0.f}, acc2 = {0.f,0.f,0.f,0.f};

  const float* xa = x + (size_t)(r0 + mh * 16 + ml) * EMBED + q * 8;
  const unsigned short* Bb = Wtu + q * 1536 + (wn * 48 + ml) * 8;

  // ping-pong named frags
  bf16x8 h0, l0, h1, l1, h2, l2;      // buffer A (even ks)
  bf16x8 g0, m0, g1, m1, g2, m2;      // buffer B (odd ks)
  float4 a0, a1, b0, b1;

  LOADB(h0, l0, h1, l1, h2, l2, 0);
  LOADA(a0, a1, 0);

  for (int ks = 0; ks < 24; ks += 2) {
    // prefetch ks+1, compute ks
    LOADB(g0, m0, g1, m1, g2, m2, ks + 1);
    LOADA(b0, b1, ks + 1);
    COMPUTE(a0, a1, h0, l0, h1, l1, h2, l2);
    // prefetch ks+2, compute ks+1
    if (ks < 22) {
      LOADB(h0, l0, h1, l1, h2, l2, ks + 2);
      LOADA(a0, a1, ks + 2);
    }
    COMPUTE(b0, b1, g0, m0, g1, m1, g2, m2);
  }

  // epilogue: bias + store. C/D layout: col = ml, row = q*4 + reg.
#define EPI(NT, ACC) do {                                                   \
    const int n = wn * 48 + (NT) * 16 + ml;                                 \
    const float bias = (n < 64) ? bq[n] : (n < 128) ? bk[n - 64] : bv[n - 128]; \
    const int row = r0 + mh * 16 + q * 4;                                   \
    C[(size_t)(row + 0) * CN + n] = ACC[0] + bias;                          \
    C[(size_t)(row + 1) * CN + n] = ACC[1] + bias;                          \
    C[(size_t)(row + 2) * CN + n] = ACC[2] + bias;                          \
    C[(size_t)(row + 3) * CN + n] = ACC[3] + bias;                          \
  } while (0)

  EPI(0, acc0); EPI(1, acc1); EPI(2, acc2);

  // fused Vsum partials: V cols are n >= 128. Per lane: 4 rows (+4x bias),
  // shfl over q-groups (16 rows per wave), one atomic per col per wave.
#define VS(NT, ACC) do {                                                    \
    const int n = wn * 48 + (NT) * 16 + ml;                                 \
    if (n >= 128) {                                                         \
      float s = ACC[0] + ACC[1] + ACC[2] + ACC[3] + 4.f * bv[n - 128];      \
      s += __shfl_xor(s, 16, 64);                                           \
      s += __shfl_xor(s, 32, 64);                                           \
      if (q == 0) atomicAdd(&Vsum[(r0 >> 12) * 64 + (n - 128)], s);         \
    }                                                                       \
  } while (0)

  VS(0, acc0); VS(1, acc1); VS(2, acc2);
}

// ---------------------------------------------------------------------------
// Per-row scores + softmax-with-zero-background + V combine (faithful quirk).
// ---------------------------------------------------------------------------
__global__ __launch_bounds__(256) void attn_kernel(const float* __restrict__ C,
                                                   const float* __restrict__ Vsum,
                                                   float* __restrict__ out) {
  const int t    = threadIdx.x;
  const int lane = t & 63;
  const int wave = t >> 6;
  const int r = blockIdx.x * 4 + wave;
  const int b = r >> 12;
  const int i = r & (NTOK - 1);

  const float q  = C[(size_t)r * CN + lane];
  const float kc = C[(size_t)r * CN + 64 + lane];
  float km = 0.f, kp = 0.f;
  if (i > 0)        km = C[(size_t)(r - 1) * CN + 64 + lane];
  if (i < NTOK - 1) kp = C[(size_t)(r + 1) * CN + 64 + lane];

  float p0 = q * km, p1 = q * kc, p2 = q * kp;
#pragma unroll
  for (int off = 32; off > 0; off >>= 1) {
    p0 += __shfl_xor(p0, off, 64);
    p1 += __shfl_xor(p1, off, 64);
    p2 += __shfl_xor(p2, off, 64);
  }

  const float s0 = (i > 0) ? p0 : 0.f;
  const float s1 = p1;
  const float s2 = (i < NTOK - 1) ? p2 : 0.f;
  const float m  = fmaxf(fmaxf(s0, s1), fmaxf(s2, 0.f));
  const float e0 = expf(s0 - m);
  const float e1 = expf(s1 - m);
  const float e2 = expf(s2 - m);
  const float ez = expf(-m);
  const float Z  = e0 + e1 + e2 + (float)(NTOK - 3) * ez;

  const size_t vb = ((size_t)b * NTOK) * CN + 128;
  const float v0 = C[vb + lane];
  const float v1 = C[vb + CN + lane];
  const float v2 = C[vb + 2 * (size_t)CN + lane];
  const float vs = Vsum[b * 64 + lane];

  out[(size_t)r * 64 + lane] =
      (e0 * v0 + e1 * v1 + e2 * v2 + ez * (vs - v0 - v1 - v2)) / Z;
}

// ---------------------------------------------------------------------------
extern "C" void kernel_launch(void* const* d_in, const int* in_sizes, int n_in,
                              void* d_out, int out_size, void* d_ws, size_t ws_size,
                              hipStream_t stream) {
  const float* x  = (const float*)d_in[0];
  const float* Wq = (const float*)d_in[1];
  const float* bq = (const float*)d_in[2];
  const float* Wk = (const float*)d_in[3];
  const float* bk = (const float*)d_in[4];
  const float* Wv = (const float*)d_in[5];
  const float* bv = (const float*)d_in[6];
  float* out = (float*)d_out;

  float* C    = (float*)d_ws;                              // 16384 x 192 fp32 (12 MiB)
  float* Vsum = C + (size_t)ROWS * CN;                     // 4 x 64
  unsigned short* Wt = (unsigned short*)(Vsum + NB * 64);  // 24 x 2 x 192 x 32 bf16 (576 KiB)

  wprep<<<72, 256, 0, stream>>>(Wq, Wk, Wv, Wt, Vsum);
  qkv_mfma<<<512, 512, 0, stream>>>(x, Wt, bq, bk, bv, C, Vsum);
  attn_kernel<<<ROWS / 4, 256, 0, stream>>>(C, Vsum, out);
}